// Round 1
// baseline (2073.027 us; speedup 1.0000x reference)
//
#include <hip/hip_runtime.h>

#define NN   100000
#define NE   1600000
#define DIM  64
#define NREL 8

// Per-(dst, rel) edge counts — depends only on edge lists, computed once.
__global__ __launch_bounds__(256) void count_k(const int* __restrict__ dst,
                                               const int* __restrict__ et,
                                               int* __restrict__ cnt, int E) {
    int i = blockIdx.x * 256 + threadIdx.x;
    if (i < E) atomicAdd(&cnt[dst[i] * NREL + et[i]], 1);
}

// out[v] = x[v] @ R + b   (wave per node, lane = output feature)
__global__ __launch_bounds__(256) void root_k(const float* __restrict__ x,
                                              const float* __restrict__ R,
                                              const float* __restrict__ b,
                                              float* __restrict__ out, int N) {
    int wid  = (blockIdx.x * 256 + threadIdx.x) >> 6;
    int lane = threadIdx.x & 63;
    if (wid >= N) return;
    wid = __builtin_amdgcn_readfirstlane(wid);          // wave-uniform -> scalar loads
    const float* xs = x + (size_t)wid * DIM;
    float acc = b[lane];
#pragma unroll
    for (int k = 0; k < DIM; ++k)
        acc = fmaf(xs[k], R[k * DIM + lane], acc);      // xs[k] via SGPR broadcast
    out[(size_t)wid * DIM + lane] = acc;
}

// Per edge: out[dst] += (x[src] @ W[et]) / max(cnt[dst,et],1)
// wave per edge, lane = output feature
__global__ __launch_bounds__(256) void edge_k(const float* __restrict__ x,
                                              const float* __restrict__ W,
                                              const int* __restrict__ srcv,
                                              const int* __restrict__ dstv,
                                              const int* __restrict__ etv,
                                              const int* __restrict__ cnt,
                                              float* __restrict__ out, int E) {
    int wid  = (blockIdx.x * 256 + threadIdx.x) >> 6;
    int lane = threadIdx.x & 63;
    if (wid >= E) return;
    int s = __builtin_amdgcn_readfirstlane(srcv[wid]);  // wave-uniform edge data
    int d = __builtin_amdgcn_readfirstlane(dstv[wid]);
    int t = __builtin_amdgcn_readfirstlane(etv[wid]);
    const float* xs = x + (size_t)s * DIM;              // scalar (SGPR) loads
    const float* w  = W + (size_t)t * DIM * DIM;        // coalesced vector loads
    float acc = 0.f;
#pragma unroll
    for (int k = 0; k < DIM; ++k)
        acc = fmaf(xs[k], w[k * DIM + lane], acc);
    float nrm = 1.0f / fmaxf((float)cnt[d * NREL + t], 1.0f);
    atomicAdd(&out[(size_t)d * DIM + lane], acc * nrm);
}

extern "C" void kernel_launch(void* const* d_in, const int* in_sizes, int n_in,
                              void* d_out, int out_size, void* d_ws, size_t ws_size,
                              hipStream_t stream) {
    const float* x  = (const float*)d_in[0];   // [N, 64]
    const float* W  = (const float*)d_in[1];   // [2, 8, 64, 64]
    const float* R  = (const float*)d_in[2];   // [2, 64, 64]
    const float* B  = (const float*)d_in[3];   // [2, 64]
    const int*   ei = (const int*)d_in[4];     // [2, E]
    const int*   et = (const int*)d_in[5];     // [E]
    const int* src = ei;
    const int* dst = ei + NE;

    float* x1  = (float*)d_ws;                                   // N*DIM f32 (25.6 MB)
    int*   cnt = (int*)((char*)d_ws + sizeof(float) * NN * DIM); // N*R  i32 ( 3.2 MB)
    float* out = (float*)d_out;

    // per-(dst,rel) counts — shared by both layers
    hipMemsetAsync(cnt, 0, sizeof(int) * NN * NREL, stream);
    count_k<<<(NE + 255) / 256, 256, 0, stream>>>(dst, et, cnt, NE);

    // layer 0: x -> x1
    root_k<<<(NN * 64) / 256 + 1, 256, 0, stream>>>(x, R, B, x1, NN);
    edge_k<<<(NE * 64) / 256, 256, 0, stream>>>(x, W, src, dst, et, cnt, x1, NE);

    // layer 1: x1 -> out
    root_k<<<(NN * 64) / 256 + 1, 256, 0, stream>>>(x1, R + DIM * DIM, B + DIM, out, NN);
    edge_k<<<(NE * 64) / 256, 256, 0, stream>>>(x1, W + NREL * DIM * DIM, src, dst, et, cnt, out, NE);
}

// Round 2
// 1256.879 us; speedup vs baseline: 1.6493x; 1.6493x over previous
//
#include <hip/hip_runtime.h>

#define NN    100000
#define NE    1600000
#define DIM   64
#define NREL  8
#define NSEG  (NN * NREL)              // 800000 (dst,rel) segments
#define CHUNK 1024
#define NBLK  ((NSEG + CHUNK - 1) / CHUNK)   // 782

// ---------------- utility ----------------
__device__ __forceinline__ float bcastf(float x, int l) {
    // wave-wide broadcast of lane l via v_readlane (SGPR), feeds v_fma v,s,v
    return __int_as_float(__builtin_amdgcn_readlane(__float_as_int(x), l));
}

// exclusive prefix over blockDim.x values (Hillis-Steele in LDS)
__device__ __forceinline__ int block_exscan(int v, int* lds) {
    int tid = threadIdx.x;
    lds[tid] = v;
    __syncthreads();
    for (int s = 1; s < (int)blockDim.x; s <<= 1) {
        int t = (tid >= s) ? lds[tid - s] : 0;
        __syncthreads();
        lds[tid] += t;
        __syncthreads();
    }
    return lds[tid] - v;
}

// ---------------- CSR build (once per call) ----------------
__global__ __launch_bounds__(256) void count_k(const int* __restrict__ dst,
                                               const int* __restrict__ et,
                                               int* __restrict__ cnt, int E) {
    int i = blockIdx.x * 256 + threadIdx.x;
    if (i < E) atomicAdd(&cnt[dst[i] * NREL + et[i]], 1);
}

__global__ __launch_bounds__(256) void scanA(const int* __restrict__ cnt,
                                             int* __restrict__ bsum) {
    __shared__ int lds[256];
    int base = blockIdx.x * CHUNK + threadIdx.x * 4;
    int s = 0;
#pragma unroll
    for (int j = 0; j < 4; ++j) { int i = base + j; if (i < NSEG) s += cnt[i]; }
    int e = block_exscan(s, lds);
    if (threadIdx.x == 255) bsum[blockIdx.x] = e + s;
}

__global__ __launch_bounds__(1024) void scanB(int* __restrict__ bsum) {
    __shared__ int lds[1024];
    int v = (threadIdx.x < NBLK) ? bsum[threadIdx.x] : 0;
    int e = block_exscan(v, lds);
    if (threadIdx.x < NBLK) bsum[threadIdx.x] = e;
}

__global__ __launch_bounds__(256) void scanC(const int* __restrict__ cnt,
                                             const int* __restrict__ bsum,
                                             int* __restrict__ off,
                                             int* __restrict__ cur) {
    __shared__ int lds[256];
    int base = blockIdx.x * CHUNK + threadIdx.x * 4;
    int v[4]; int s = 0;
#pragma unroll
    for (int j = 0; j < 4; ++j) { int i = base + j; v[j] = (i < NSEG) ? cnt[i] : 0; s += v[j]; }
    int e = block_exscan(s, lds) + bsum[blockIdx.x];
#pragma unroll
    for (int j = 0; j < 4; ++j) {
        int i = base + j;
        if (i < NSEG) { off[i] = e; cur[i] = e; e += v[j]; }
    }
}

__global__ __launch_bounds__(256) void scatter_k(const int* __restrict__ src,
                                                 const int* __restrict__ dst,
                                                 const int* __restrict__ et,
                                                 int* __restrict__ cur,
                                                 int* __restrict__ es, int E) {
    int i = blockIdx.x * 256 + threadIdx.x;
    if (i < E) {
        int c = dst[i] * NREL + et[i];
        int p = atomicAdd(&cur[c], 1);
        es[p] = src[i];
    }
}

// ---------------- fused RGCN layer ----------------
// wave per dst: aggregate per-relation means in registers (lane = in-dim),
// then transform against LDS-staged W (8 rel + root), lane = out-dim.
__global__ __launch_bounds__(1024) void layer_k(
    const float* __restrict__ xin, const float* __restrict__ Wg,
    const float* __restrict__ Rg, const float* __restrict__ bg,
    const int* __restrict__ off, const int* __restrict__ cnt,
    const int* __restrict__ es, float* __restrict__ out)
{
    __shared__ float Wl[9 * DIM * DIM];            // 147456 B
    for (int i = threadIdx.x; i < 8 * DIM * DIM; i += 1024) Wl[i] = Wg[i];
    for (int i = threadIdx.x; i < DIM * DIM; i += 1024) Wl[8 * DIM * DIM + i] = Rg[i];
    __syncthreads();

    const int lane = threadIdx.x & 63;
    const int wv   = threadIdx.x >> 6;

    for (int dst = blockIdx.x * 16 + wv; dst < NN; dst += gridDim.x * 16) {
        // ---- aggregate: m[r] = mean of x[src] over segment (dst,r) ----
        float m[NREL];
#pragma unroll
        for (int r = 0; r < NREL; ++r) {
            int c  = dst * NREL + r;
            int s0 = __builtin_amdgcn_readfirstlane(off[c]);
            int n  = __builtin_amdgcn_readfirstlane(cnt[c]);
            float acc = 0.f;
            for (int p = s0; p < s0 + n; ++p) {
                int sv = __builtin_amdgcn_readfirstlane(es[p]);   // SGPR src id
                acc += xin[(size_t)sv * DIM + lane];
            }
            m[r] = acc * (1.0f / fmaxf((float)n, 1.0f));
        }
        float xr = xin[(size_t)dst * DIM + lane];

        // ---- transform: o = b + sum_r m[r] @ W[r] + xr @ root ----
        float o0 = bg[lane], o1 = 0.f, o2 = 0.f, o3 = 0.f;
#pragma unroll
        for (int r = 0; r < NREL; ++r) {
            const float* wr = &Wl[r * DIM * DIM];
#pragma unroll 4
            for (int d = 0; d < DIM; d += 4) {
                o0 = fmaf(bcastf(m[r], d + 0), wr[(d + 0) * DIM + lane], o0);
                o1 = fmaf(bcastf(m[r], d + 1), wr[(d + 1) * DIM + lane], o1);
                o2 = fmaf(bcastf(m[r], d + 2), wr[(d + 2) * DIM + lane], o2);
                o3 = fmaf(bcastf(m[r], d + 3), wr[(d + 3) * DIM + lane], o3);
            }
        }
        {
            const float* wr = &Wl[8 * DIM * DIM];
#pragma unroll 4
            for (int d = 0; d < DIM; d += 4) {
                o0 = fmaf(bcastf(xr, d + 0), wr[(d + 0) * DIM + lane], o0);
                o1 = fmaf(bcastf(xr, d + 1), wr[(d + 1) * DIM + lane], o1);
                o2 = fmaf(bcastf(xr, d + 2), wr[(d + 2) * DIM + lane], o2);
                o3 = fmaf(bcastf(xr, d + 3), wr[(d + 3) * DIM + lane], o3);
            }
        }
        out[(size_t)dst * DIM + lane] = (o0 + o1) + (o2 + o3);
    }
}

// ---------------- fallback (round-1, needs only 28.8 MB ws) ----------------
__global__ __launch_bounds__(256) void root_k(const float* __restrict__ x,
                                              const float* __restrict__ R,
                                              const float* __restrict__ b,
                                              float* __restrict__ out, int N) {
    int wid  = (blockIdx.x * 256 + threadIdx.x) >> 6;
    int lane = threadIdx.x & 63;
    if (wid >= N) return;
    wid = __builtin_amdgcn_readfirstlane(wid);
    const float* xs = x + (size_t)wid * DIM;
    float acc = b[lane];
#pragma unroll
    for (int k = 0; k < DIM; ++k)
        acc = fmaf(xs[k], R[k * DIM + lane], acc);
    out[(size_t)wid * DIM + lane] = acc;
}

__global__ __launch_bounds__(256) void edge_k(const float* __restrict__ x,
                                              const float* __restrict__ W,
                                              const int* __restrict__ srcv,
                                              const int* __restrict__ dstv,
                                              const int* __restrict__ etv,
                                              const int* __restrict__ cnt,
                                              float* __restrict__ out, int E) {
    int wid  = (blockIdx.x * 256 + threadIdx.x) >> 6;
    int lane = threadIdx.x & 63;
    if (wid >= E) return;
    int s = __builtin_amdgcn_readfirstlane(srcv[wid]);
    int d = __builtin_amdgcn_readfirstlane(dstv[wid]);
    int t = __builtin_amdgcn_readfirstlane(etv[wid]);
    const float* xs = x + (size_t)s * DIM;
    const float* w  = W + (size_t)t * DIM * DIM;
    float acc = 0.f;
#pragma unroll
    for (int k = 0; k < DIM; ++k)
        acc = fmaf(xs[k], w[k * DIM + lane], acc);
    float nrm = 1.0f / fmaxf((float)cnt[d * NREL + t], 1.0f);
    atomicAdd(&out[(size_t)d * DIM + lane], acc * nrm);
}

// ---------------- launch ----------------
extern "C" void kernel_launch(void* const* d_in, const int* in_sizes, int n_in,
                              void* d_out, int out_size, void* d_ws, size_t ws_size,
                              hipStream_t stream) {
    const float* x  = (const float*)d_in[0];   // [N, 64]
    const float* W  = (const float*)d_in[1];   // [2, 8, 64, 64]
    const float* R  = (const float*)d_in[2];   // [2, 64, 64]
    const float* B  = (const float*)d_in[3];   // [2, 64]
    const int*   ei = (const int*)d_in[4];     // [2, E]
    const int*   et = (const int*)d_in[5];     // [E]
    const int* src = ei;
    const int* dst = ei + NE;
    float* out = (float*)d_out;

    char* ws = (char*)d_ws;
    float* x1  = (float*)(ws + 0);                       // 25,600,000 B
    int*   cnt = (int*)  (ws + 25600000);                //  3,200,000 B
    int*   off = (int*)  (ws + 28800000);                //  3,200,000 B
    int*   cur = (int*)  (ws + 32000000);                //  3,200,000 B
    int*   es  = (int*)  (ws + 35200000);                //  6,400,000 B
    int*   bsum= (int*)  (ws + 41600000);                //      4,096 B
    const size_t FAST_WS = 41604096;

    hipMemsetAsync(cnt, 0, sizeof(int) * NSEG, stream);
    count_k<<<(NE + 255) / 256, 256, 0, stream>>>(dst, et, cnt, NE);

    if (ws_size >= FAST_WS) {
        // CSR sort by (dst, rel)
        scanA<<<NBLK, 256, 0, stream>>>(cnt, bsum);
        scanB<<<1, 1024, 0, stream>>>(bsum);
        scanC<<<NBLK, 256, 0, stream>>>(cnt, bsum, off, cur);
        scatter_k<<<(NE + 255) / 256, 256, 0, stream>>>(src, dst, et, cur, es, NE);

        layer_k<<<2048, 1024, 0, stream>>>(x, W, R, B, off, cnt, es, x1);
        layer_k<<<2048, 1024, 0, stream>>>(x1, W + NREL * DIM * DIM, R + DIM * DIM,
                                           B + DIM, off, cnt, es, out);
    } else {
        // fallback: round-1 per-edge path
        root_k<<<(NN * 64) / 256 + 1, 256, 0, stream>>>(x, R, B, x1, NN);
        edge_k<<<(NE * 64) / 256, 256, 0, stream>>>(x, W, src, dst, et, cnt, x1, NE);
        root_k<<<(NN * 64) / 256 + 1, 256, 0, stream>>>(x1, R + DIM * DIM, B + DIM, out, NN);
        edge_k<<<(NE * 64) / 256, 256, 0, stream>>>(x1, W + NREL * DIM * DIM, src, dst, et, cnt, out, NE);
    }
}

// Round 3
// 726.214 us; speedup vs baseline: 2.8546x; 1.7307x over previous
//
#include <hip/hip_runtime.h>

#define NN    100000
#define NE    1600000
#define DIM   64
#define NREL  8
#define NSEG  (NN * NREL)                       // 800000 (dst,rel) segments
#define NTOT  (NSEG + 1)                        // off[] has a sentinel end
#define CHUNK 1024
#define NBLK  ((NTOT + CHUNK - 1) / CHUNK)      // 782
#define KTOT  (9 * DIM)                         // 576: 8 relations + root
#define APAD  (KTOT + 8)                        // 584 bf16: +16B row pad

typedef unsigned short ushort;
using short8 = __attribute__((ext_vector_type(8))) short;
using f32x4  = __attribute__((ext_vector_type(4))) float;

__device__ __forceinline__ ushort f2bf(float v) {   // f32 -> bf16 RNE
    unsigned b = __float_as_uint(v);
    return (ushort)((b + 0x7FFFu + ((b >> 16) & 1u)) >> 16);
}

// exclusive prefix over blockDim.x values
__device__ __forceinline__ int block_exscan(int v, int* lds) {
    int tid = threadIdx.x;
    lds[tid] = v;
    __syncthreads();
    for (int s = 1; s < (int)blockDim.x; s <<= 1) {
        int t = (tid >= s) ? lds[tid - s] : 0;
        __syncthreads();
        lds[tid] += t;
        __syncthreads();
    }
    return lds[tid] - v;
}

// ---------------- CSR build ----------------
__global__ __launch_bounds__(256) void count_k(const int* __restrict__ dst,
                                               const int* __restrict__ et,
                                               int* __restrict__ cnt, int E) {
    int i = blockIdx.x * 256 + threadIdx.x;
    if (i < E) atomicAdd(&cnt[dst[i] * NREL + et[i]], 1);
}

__global__ __launch_bounds__(256) void scanA(const int* __restrict__ cnt,
                                             int* __restrict__ bsum) {
    __shared__ int lds[256];
    int base = blockIdx.x * CHUNK + threadIdx.x * 4;
    int s = 0;
#pragma unroll
    for (int j = 0; j < 4; ++j) { int i = base + j; if (i < NSEG) s += cnt[i]; }
    int e = block_exscan(s, lds);
    if (threadIdx.x == 255) bsum[blockIdx.x] = e + s;
}

__global__ __launch_bounds__(1024) void scanB(int* __restrict__ bsum) {
    __shared__ int lds[1024];
    int v = (threadIdx.x < NBLK) ? bsum[threadIdx.x] : 0;
    int e = block_exscan(v, lds);
    if (threadIdx.x < NBLK) bsum[threadIdx.x] = e;
}

__global__ __launch_bounds__(256) void scanC(const int* __restrict__ cnt,
                                             const int* __restrict__ bsum,
                                             int* __restrict__ off,
                                             int* __restrict__ cur) {
    __shared__ int lds[256];
    int base = blockIdx.x * CHUNK + threadIdx.x * 4;
    int v[4]; int s = 0;
#pragma unroll
    for (int j = 0; j < 4; ++j) { int i = base + j; v[j] = (i < NSEG) ? cnt[i] : 0; s += v[j]; }
    int e = block_exscan(s, lds) + bsum[blockIdx.x];
#pragma unroll
    for (int j = 0; j < 4; ++j) {
        int i = base + j;
        if (i < NSEG)       { off[i] = e; cur[i] = e; e += v[j]; }
        else if (i == NSEG) { off[i] = e; }                       // sentinel = NE
    }
}

__global__ __launch_bounds__(256) void scatter_k(const int* __restrict__ src,
                                                 const int* __restrict__ dst,
                                                 const int* __restrict__ et,
                                                 int* __restrict__ cur,
                                                 int* __restrict__ es, int E) {
    int i = blockIdx.x * 256 + threadIdx.x;
    if (i < E) {
        int c = dst[i] * NREL + et[i];
        int p = atomicAdd(&cur[c], 1);
        es[p] = src[i];
    }
}

// ---------------- B-stack transpose: Bt[l][n][k] = Bs[l][k][n] in bf16 ----------------
// Bs = concat_k(W[l][r][d][*], root[l][d][*]); k = r*64+d (r<8), 512+d (root)
__global__ __launch_bounds__(256) void btk(const float* __restrict__ W,
                                           const float* __restrict__ R,
                                           ushort* __restrict__ BtG) {
    int idx = blockIdx.x * 256 + threadIdx.x;     // [2][64][576]
    if (idx >= 2 * DIM * KTOT) return;
    int k = idx % KTOT;
    int n = (idx / KTOT) & (DIM - 1);
    int l = idx / (KTOT * DIM);
    float v;
    if (k < 8 * DIM) v = W[(((size_t)l * NREL + (k >> 6)) * DIM + (k & 63)) * DIM + n];
    else             v = R[((size_t)l * DIM + (k - 8 * DIM)) * DIM + n];
    BtG[idx] = f2bf(v);
}

// ---------------- fused RGCN layer: aggregate -> MFMA GEMM ----------------
// block = 512 thr (8 waves), 64 dst rows. LDS A-tile [64][584] bf16 = 74.75 KB
// -> 2 blocks/CU. GEMM: 16 tiles of 16x16, 2 tiles/wave, B-frags from global.
__global__ __launch_bounds__(512, 4) void layer_k(
    const float* __restrict__ xin, const ushort* __restrict__ BtG,
    const float* __restrict__ bias, const int* __restrict__ off,
    const int* __restrict__ es, float* __restrict__ out)
{
    __shared__ ushort A[64 * APAD];
    const int lane = threadIdx.x & 63;
    const int wv   = threadIdx.x >> 6;
    const int base = blockIdx.x * 64;

    // ---- phase 1: aggregate 8 dsts per wave; lane = feature ----
    for (int i = 0; i < 8; ++i) {
        int arow = wv * 8 + i;
        int dst  = base + arow;
        ushort* Ar = &A[arow * APAD];
        if (dst < NN) {
            int c0 = dst * NREL;
            int offv = off[c0 + (lane < NREL ? lane : NREL)];   // lanes 0..8 -> seg bounds
            int idsbase = __builtin_amdgcn_readlane(offv, 0);
            int ids = es[min(idsbase + lane, NE - 1)];          // 64 edge ids / load
            for (int r = 0; r < NREL; ++r) {
                int s0 = __builtin_amdgcn_readlane(offv, r);
                int s1 = __builtin_amdgcn_readlane(offv, r + 1);
                float acc = 0.f;
                for (int p = s0; p < s1; ++p) {
                    if (p - idsbase >= 64) {
                        idsbase = p;
                        ids = es[min(idsbase + lane, NE - 1)];
                    }
                    int sv = __builtin_amdgcn_readlane(ids, p - idsbase);  // SGPR src id
                    acc += xin[(size_t)sv * DIM + lane];                   // coalesced row
                }
                float n = (float)(s1 - s0);
                Ar[r * DIM + lane] = f2bf(acc * (1.0f / fmaxf(n, 1.0f)));
            }
            Ar[8 * DIM + lane] = f2bf(xin[(size_t)dst * DIM + lane]);      // root slot
        } else {
#pragma unroll
            for (int r = 0; r < 9; ++r) Ar[r * DIM + lane] = 0;
        }
    }
    __syncthreads();

    // ---- phase 2: C[64x64] = A[64x576] @ Bstack[576x64] ----
    const int l15 = lane & 15, hw = lane >> 4;
    const int tid0 = wv * 2;                 // two N-adjacent 16x16 tiles per wave
    const int tm = tid0 >> 2, tn0 = tid0 & 3;
    const ushort* Arow = &A[(tm * 16 + l15) * APAD + hw * 8];
    const ushort* B0   = &BtG[(size_t)(tn0 * 16 + l15) * KTOT + hw * 8];
    const ushort* B1   = B0 + 16 * KTOT;
    f32x4 acc0 = {0.f, 0.f, 0.f, 0.f}, acc1 = {0.f, 0.f, 0.f, 0.f};
#pragma unroll
    for (int ks = 0; ks < KTOT / 32; ++ks) {         // 18 K-steps of 32
        short8 af = *(const short8*)(Arow + ks * 32);
        short8 b0 = *(const short8*)(B0 + ks * 32);
        short8 b1 = *(const short8*)(B1 + ks * 32);
        acc0 = __builtin_amdgcn_mfma_f32_16x16x32_bf16(af, b0, acc0, 0, 0, 0);
        acc1 = __builtin_amdgcn_mfma_f32_16x16x32_bf16(af, b1, acc1, 0, 0, 0);
    }
    // C/D: col = lane&15, row = (lane>>4)*4 + reg   [m89-verified]
    int col0 = tn0 * 16 + l15;
    int r0   = tm * 16 + hw * 4;
    float bv0 = bias[col0], bv1 = bias[col0 + 16];
#pragma unroll
    for (int j = 0; j < 4; ++j) {
        int row = base + r0 + j;
        if (row < NN) {
            out[(size_t)row * DIM + col0]      = acc0[j] + bv0;
            out[(size_t)row * DIM + col0 + 16] = acc1[j] + bv1;
        }
    }
}

// ---------------- fallback (small ws): round-1 per-edge path ----------------
__global__ __launch_bounds__(256) void root_k(const float* __restrict__ x,
                                              const float* __restrict__ R,
                                              const float* __restrict__ b,
                                              float* __restrict__ out, int N) {
    int wid  = (blockIdx.x * 256 + threadIdx.x) >> 6;
    int lane = threadIdx.x & 63;
    if (wid >= N) return;
    wid = __builtin_amdgcn_readfirstlane(wid);
    const float* xs = x + (size_t)wid * DIM;
    float acc = b[lane];
#pragma unroll
    for (int k = 0; k < DIM; ++k)
        acc = fmaf(xs[k], R[k * DIM + lane], acc);
    out[(size_t)wid * DIM + lane] = acc;
}

__global__ __launch_bounds__(256) void edge_k(const float* __restrict__ x,
                                              const float* __restrict__ W,
                                              const int* __restrict__ srcv,
                                              const int* __restrict__ dstv,
                                              const int* __restrict__ etv,
                                              const int* __restrict__ cnt,
                                              float* __restrict__ out, int E) {
    int wid  = (blockIdx.x * 256 + threadIdx.x) >> 6;
    int lane = threadIdx.x & 63;
    if (wid >= E) return;
    int s = __builtin_amdgcn_readfirstlane(srcv[wid]);
    int d = __builtin_amdgcn_readfirstlane(dstv[wid]);
    int t = __builtin_amdgcn_readfirstlane(etv[wid]);
    const float* xs = x + (size_t)s * DIM;
    const float* w  = W + (size_t)t * DIM * DIM;
    float acc = 0.f;
#pragma unroll
    for (int k = 0; k < DIM; ++k)
        acc = fmaf(xs[k], w[k * DIM + lane], acc);
    float nrm = 1.0f / fmaxf((float)cnt[d * NREL + t], 1.0f);
    atomicAdd(&out[(size_t)d * DIM + lane], acc * nrm);
}

// ---------------- launch ----------------
extern "C" void kernel_launch(void* const* d_in, const int* in_sizes, int n_in,
                              void* d_out, int out_size, void* d_ws, size_t ws_size,
                              hipStream_t stream) {
    const float* x  = (const float*)d_in[0];   // [N, 64]
    const float* W  = (const float*)d_in[1];   // [2, 8, 64, 64]
    const float* R  = (const float*)d_in[2];   // [2, 64, 64]
    const float* B  = (const float*)d_in[3];   // [2, 64]
    const int*   ei = (const int*)d_in[4];     // [2, E]
    const int*   et = (const int*)d_in[5];     // [E]
    const int* src = ei;
    const int* dst = ei + NE;
    float* out = (float*)d_out;

    char* ws = (char*)d_ws;
    float* x1  = (float*)(ws + 0);             // 25,600,000 B
    int*   cnt = (int*)  (ws + 25600000);      //  3,200,000 B
    int*   off = (int*)  (ws + 28800000);      //  3,200,004 B (+sentinel)
    int*   cur = (int*)  (ws + 32000016);      //  3,200,000 B (dead after scatter)
    int*   es  = (int*)  (ws + 35200016);      //  6,400,000 B
    int*   bsum= (int*)  (ws + 41600016);      //      3,128 B
    ushort* BtG= (ushort*)(ws + 32000016);     // alias over cur: 147,456 B
    const size_t FAST_WS = 41604096;

    hipMemsetAsync(cnt, 0, sizeof(int) * NSEG, stream);
    count_k<<<(NE + 255) / 256, 256, 0, stream>>>(dst, et, cnt, NE);

    if (ws_size >= FAST_WS) {
        scanA<<<NBLK, 256, 0, stream>>>(cnt, bsum);
        scanB<<<1, 1024, 0, stream>>>(bsum);
        scanC<<<NBLK, 256, 0, stream>>>(cnt, bsum, off, cur);
        scatter_k<<<(NE + 255) / 256, 256, 0, stream>>>(src, dst, et, cur, es, NE);
        btk<<<(2 * DIM * KTOT + 255) / 256, 256, 0, stream>>>(W, R, BtG);  // after scatter (aliases cur)

        int nblk = (NN + 63) / 64;   // 1563
        layer_k<<<nblk, 512, 0, stream>>>(x,  BtG,              B,       off, es, x1);
        layer_k<<<nblk, 512, 0, stream>>>(x1, BtG + DIM * KTOT, B + DIM, off, es, out);
    } else {
        root_k<<<(NN * 64) / 256 + 1, 256, 0, stream>>>(x, R, B, x1, NN);
        edge_k<<<(NE * 64) / 256, 256, 0, stream>>>(x, W, src, dst, et, cnt, x1, NE);
        root_k<<<(NN * 64) / 256 + 1, 256, 0, stream>>>(x1, R + DIM * DIM, B + DIM, out, NN);
        edge_k<<<(NE * 64) / 256, 256, 0, stream>>>(x1, W + NREL * DIM * DIM, src, dst, et, cnt, out, NE);
    }
}

// Round 4
// 671.898 us; speedup vs baseline: 3.0853x; 1.0808x over previous
//
#include <hip/hip_runtime.h>

#define NN    100000
#define NE    1600000
#define DIM   64
#define NREL  8
#define NSEG  (NN * NREL)                       // 800000 (dst,rel) segments
#define NTOT  (NSEG + 1)                        // off[] has a sentinel end
#define CHUNK 1024
#define NBLK  ((NTOT + CHUNK - 1) / CHUNK)      // 782
#define KTOT  (9 * DIM)                         // 576: 8 relations + root
#define APAD  (KTOT + 8)                        // 584 bf16: +16B row pad

typedef unsigned short ushort;
using short8 = __attribute__((ext_vector_type(8))) short;
using f32x4  = __attribute__((ext_vector_type(4))) float;

__device__ __forceinline__ ushort f2bf(float v) {   // f32 -> bf16 RNE
    unsigned b = __float_as_uint(v);
    return (ushort)((b + 0x7FFFu + ((b >> 16) & 1u)) >> 16);
}

// exclusive prefix over blockDim.x values
__device__ __forceinline__ int block_exscan(int v, int* lds) {
    int tid = threadIdx.x;
    lds[tid] = v;
    __syncthreads();
    for (int s = 1; s < (int)blockDim.x; s <<= 1) {
        int t = (tid >= s) ? lds[tid - s] : 0;
        __syncthreads();
        lds[tid] += t;
        __syncthreads();
    }
    return lds[tid] - v;
}

// ---------------- CSR build ----------------
__global__ __launch_bounds__(256) void count_k(const int* __restrict__ dst,
                                               const int* __restrict__ et,
                                               int* __restrict__ cnt, int E) {
    int i = blockIdx.x * 256 + threadIdx.x;
    if (i < E) atomicAdd(&cnt[dst[i] * NREL + et[i]], 1);
}

__global__ __launch_bounds__(256) void scanA(const int* __restrict__ cnt,
                                             int* __restrict__ bsum) {
    __shared__ int lds[256];
    int base = blockIdx.x * CHUNK + threadIdx.x * 4;
    int s = 0;
#pragma unroll
    for (int j = 0; j < 4; ++j) { int i = base + j; if (i < NSEG) s += cnt[i]; }
    int e = block_exscan(s, lds);
    if (threadIdx.x == 255) bsum[blockIdx.x] = e + s;
}

__global__ __launch_bounds__(1024) void scanB(int* __restrict__ bsum) {
    __shared__ int lds[1024];
    int v = (threadIdx.x < NBLK) ? bsum[threadIdx.x] : 0;
    int e = block_exscan(v, lds);
    if (threadIdx.x < NBLK) bsum[threadIdx.x] = e;
}

__global__ __launch_bounds__(256) void scanC(const int* __restrict__ cnt,
                                             const int* __restrict__ bsum,
                                             int* __restrict__ off,
                                             int* __restrict__ cur) {
    __shared__ int lds[256];
    int base = blockIdx.x * CHUNK + threadIdx.x * 4;
    int v[4]; int s = 0;
#pragma unroll
    for (int j = 0; j < 4; ++j) { int i = base + j; v[j] = (i < NSEG) ? cnt[i] : 0; s += v[j]; }
    int e = block_exscan(s, lds) + bsum[blockIdx.x];
#pragma unroll
    for (int j = 0; j < 4; ++j) {
        int i = base + j;
        if (i < NSEG)       { off[i] = e; cur[i] = e; e += v[j]; }
        else if (i == NSEG) { off[i] = e; }                       // sentinel = NE
    }
}

__global__ __launch_bounds__(256) void scatter_k(const int* __restrict__ src,
                                                 const int* __restrict__ dst,
                                                 const int* __restrict__ et,
                                                 int* __restrict__ cur,
                                                 int* __restrict__ es, int E) {
    int i = blockIdx.x * 256 + threadIdx.x;
    if (i < E) {
        int c = dst[i] * NREL + et[i];
        int p = atomicAdd(&cur[c], 1);
        es[p] = src[i];
    }
}

// ---------------- B-stack transpose: Bt[l][n][k] = Bs[l][k][n] in bf16 ----------------
__global__ __launch_bounds__(256) void btk(const float* __restrict__ W,
                                           const float* __restrict__ R,
                                           ushort* __restrict__ BtG) {
    int idx = blockIdx.x * 256 + threadIdx.x;     // [2][64][576]
    if (idx >= 2 * DIM * KTOT) return;
    int k = idx % KTOT;
    int n = (idx / KTOT) & (DIM - 1);
    int l = idx / (KTOT * DIM);
    float v;
    if (k < 8 * DIM) v = W[(((size_t)l * NREL + (k >> 6)) * DIM + (k & 63)) * DIM + n];
    else             v = R[((size_t)l * DIM + (k - 8 * DIM)) * DIM + n];
    BtG[idx] = f2bf(v);
}

// ---------------- fused RGCN layer: pipelined gather -> MFMA GEMM ----------------
// block = 512 thr (8 waves), 64 dst rows. Each wave owns 8 consecutive dsts =
// one contiguous CSR range; 8-deep software-pipelined row gather.
__global__ __launch_bounds__(512, 4) void layer_k(
    const float* __restrict__ xin, const ushort* __restrict__ BtG,
    const float* __restrict__ bias, const int* __restrict__ off,
    const int* __restrict__ es, float* __restrict__ out)
{
    __shared__ ushort A[64 * APAD];
    const int lane = threadIdx.x & 63;
    const int wv   = threadIdx.x >> 6;
    const int base = blockIdx.x * 64;
    const int d0   = base + wv * 8;              // first dst of this wave
    const int nds  = min(8, NN - d0);            // valid dsts (may be <= 0)
    ushort* Aw = &A[wv * 8 * APAD];

    if (nds > 0) {
        const int c0   = d0 * NREL;
        const int nseg = nds * NREL;
        int s1v = off[min(c0 + lane + 1, NSEG)];             // segment ends
        int pBase = off[min(c0, NSEG)];
        pBase = __builtin_amdgcn_readfirstlane(pBase);
        int pEnd  = __builtin_amdgcn_readlane(s1v, nseg - 1);

        // root rows: issue early, consume after edge loop
        float xroot[8];
#pragma unroll
        for (int i = 0; i < 8; ++i)
            xroot[i] = xin[(size_t)min(d0 + i, NN - 1) * DIM + lane];

        int idsbase = pBase;
        int ids = es[min(idsbase + lane, NE - 1)];

        float q0 = 0.f, q1 = 0.f, q2 = 0.f, q3 = 0.f,
              q4 = 0.f, q5 = 0.f, q6 = 0.f, q7 = 0.f;
        {   // prime 8-deep pipeline (idx < 64 guaranteed here)
            int pf = pBase;
#define PRIME(Q) if (pf < pEnd) { int idx = pf - idsbase;                     \
        int sv = __builtin_amdgcn_readlane(ids, idx);                         \
        Q = xin[(size_t)sv * DIM + lane]; } ++pf;
            PRIME(q0) PRIME(q1) PRIME(q2) PRIME(q3)
            PRIME(q4) PRIME(q5) PRIME(q6) PRIME(q7)
#undef PRIME
        }
        int seg = 0, segStart = pBase, p = pBase;
        int se = __builtin_amdgcn_readlane(s1v, 0);
        float acc = 0.f;

#define STEP(Q) {                                                             \
        while (p == se) {   /* wave-uniform flush (handles empty segs) */     \
            int n = se - segStart;                                           \
            float invn = (n > 0) ? 1.0f / (float)n : 0.f;                     \
            Aw[(seg >> 3) * APAD + (seg & 7) * DIM + lane] = f2bf(acc * invn);\
            acc = 0.f; segStart = p;                                          \
            if (++seg >= nseg) goto agg_done;                                 \
            se = __builtin_amdgcn_readlane(s1v, seg);                         \
        }                                                                     \
        acc += Q;                                                             \
        int pn = p + 8;                                                       \
        if (pn < pEnd) {                                                      \
            int idx = pn - idsbase;                                           \
            if (idx >= 64) { idsbase = pn;                                    \
                ids = es[min(idsbase + lane, NE - 1)]; idx = 0; }             \
            int sv = __builtin_amdgcn_readlane(ids, idx);                     \
            Q = xin[(size_t)sv * DIM + lane];                                 \
        }                                                                     \
        ++p; }

        for (;;) { STEP(q0) STEP(q1) STEP(q2) STEP(q3)
                   STEP(q4) STEP(q5) STEP(q6) STEP(q7) }
agg_done: ;
#undef STEP

        // root slots + zero any tail rows
#pragma unroll
        for (int i = 0; i < 8; ++i) {
            if (i < nds) Aw[i * APAD + 8 * DIM + lane] = f2bf(xroot[i]);
            else {
#pragma unroll
                for (int r = 0; r < 9; ++r) Aw[i * APAD + r * DIM + lane] = 0;
            }
        }
    } else {
#pragma unroll
        for (int i = 0; i < 8; ++i)
#pragma unroll
            for (int r = 0; r < 9; ++r) Aw[i * APAD + r * DIM + lane] = 0;
    }
    __syncthreads();

    // ---- phase 2: C[64x64] = A[64x576] @ Bstack[576x64] ----
    const int l15 = lane & 15, hw = lane >> 4;
    const int tid0 = wv * 2;                 // two N-adjacent 16x16 tiles per wave
    const int tm = tid0 >> 2, tn0 = tid0 & 3;
    const ushort* Arow = &A[(tm * 16 + l15) * APAD + hw * 8];
    const ushort* B0   = &BtG[(size_t)(tn0 * 16 + l15) * KTOT + hw * 8];
    const ushort* B1   = B0 + 16 * KTOT;
    f32x4 acc0 = {0.f, 0.f, 0.f, 0.f}, acc1 = {0.f, 0.f, 0.f, 0.f};
#pragma unroll
    for (int ks = 0; ks < KTOT / 32; ++ks) {         // 18 K-steps of 32
        short8 af = *(const short8*)(Arow + ks * 32);
        short8 b0 = *(const short8*)(B0 + ks * 32);
        short8 b1 = *(const short8*)(B1 + ks * 32);
        acc0 = __builtin_amdgcn_mfma_f32_16x16x32_bf16(af, b0, acc0, 0, 0, 0);
        acc1 = __builtin_amdgcn_mfma_f32_16x16x32_bf16(af, b1, acc1, 0, 0, 0);
    }
    // C/D: col = lane&15, row = (lane>>4)*4 + reg   [m89-verified]
    int col0 = tn0 * 16 + l15;
    int r0   = tm * 16 + hw * 4;
    float bv0 = bias[col0], bv1 = bias[col0 + 16];
#pragma unroll
    for (int j = 0; j < 4; ++j) {
        int row = base + r0 + j;
        if (row < NN) {
            out[(size_t)row * DIM + col0]      = acc0[j] + bv0;
            out[(size_t)row * DIM + col0 + 16] = acc1[j] + bv1;
        }
    }
}

// ---------------- fallback (small ws): round-1 per-edge path ----------------
__global__ __launch_bounds__(256) void root_k(const float* __restrict__ x,
                                              const float* __restrict__ R,
                                              const float* __restrict__ b,
                                              float* __restrict__ out, int N) {
    int wid  = (blockIdx.x * 256 + threadIdx.x) >> 6;
    int lane = threadIdx.x & 63;
    if (wid >= N) return;
    wid = __builtin_amdgcn_readfirstlane(wid);
    const float* xs = x + (size_t)wid * DIM;
    float acc = b[lane];
#pragma unroll
    for (int k = 0; k < DIM; ++k)
        acc = fmaf(xs[k], R[k * DIM + lane], acc);
    out[(size_t)wid * DIM + lane] = acc;
}

__global__ __launch_bounds__(256) void edge_k(const float* __restrict__ x,
                                              const float* __restrict__ W,
                                              const int* __restrict__ srcv,
                                              const int* __restrict__ dstv,
                                              const int* __restrict__ etv,
                                              const int* __restrict__ cnt,
                                              float* __restrict__ out, int E) {
    int wid  = (blockIdx.x * 256 + threadIdx.x) >> 6;
    int lane = threadIdx.x & 63;
    if (wid >= E) return;
    int s = __builtin_amdgcn_readfirstlane(srcv[wid]);
    int d = __builtin_amdgcn_readfirstlane(dstv[wid]);
    int t = __builtin_amdgcn_readfirstlane(etv[wid]);
    const float* xs = x + (size_t)s * DIM;
    const float* w  = W + (size_t)t * DIM * DIM;
    float acc = 0.f;
#pragma unroll
    for (int k = 0; k < DIM; ++k)
        acc = fmaf(xs[k], w[k * DIM + lane], acc);
    float nrm = 1.0f / fmaxf((float)cnt[d * NREL + t], 1.0f);
    atomicAdd(&out[(size_t)d * DIM + lane], acc * nrm);
}

// ---------------- launch ----------------
extern "C" void kernel_launch(void* const* d_in, const int* in_sizes, int n_in,
                              void* d_out, int out_size, void* d_ws, size_t ws_size,
                              hipStream_t stream) {
    const float* x  = (const float*)d_in[0];   // [N, 64]
    const float* W  = (const float*)d_in[1];   // [2, 8, 64, 64]
    const float* R  = (const float*)d_in[2];   // [2, 64, 64]
    const float* B  = (const float*)d_in[3];   // [2, 64]
    const int*   ei = (const int*)d_in[4];     // [2, E]
    const int*   et = (const int*)d_in[5];     // [E]
    const int* src = ei;
    const int* dst = ei + NE;
    float* out = (float*)d_out;

    char* ws = (char*)d_ws;
    float* x1  = (float*)(ws + 0);             // 25,600,000 B
    int*   cnt = (int*)  (ws + 25600000);      //  3,200,000 B
    int*   off = (int*)  (ws + 28800000);      //  3,200,004 B (+sentinel)
    int*   cur = (int*)  (ws + 32000016);      //  3,200,000 B (dead after scatter)
    int*   es  = (int*)  (ws + 35200016);      //  6,400,000 B
    int*   bsum= (int*)  (ws + 41600016);      //      3,128 B
    ushort* BtG= (ushort*)(ws + 32000016);     // alias over cur: 147,456 B
    const size_t FAST_WS = 41604096;

    hipMemsetAsync(cnt, 0, sizeof(int) * NSEG, stream);
    count_k<<<(NE + 255) / 256, 256, 0, stream>>>(dst, et, cnt, NE);

    if (ws_size >= FAST_WS) {
        scanA<<<NBLK, 256, 0, stream>>>(cnt, bsum);
        scanB<<<1, 1024, 0, stream>>>(bsum);
        scanC<<<NBLK, 256, 0, stream>>>(cnt, bsum, off, cur);
        scatter_k<<<(NE + 255) / 256, 256, 0, stream>>>(src, dst, et, cur, es, NE);
        btk<<<(2 * DIM * KTOT + 255) / 256, 256, 0, stream>>>(W, R, BtG);  // after scatter (aliases cur)

        int nblk = (NN + 63) / 64;   // 1563
        layer_k<<<nblk, 512, 0, stream>>>(x,  BtG,              B,       off, es, x1);
        layer_k<<<nblk, 512, 0, stream>>>(x1, BtG + DIM * KTOT, B + DIM, off, es, out);
    } else {
        root_k<<<(NN * 64) / 256 + 1, 256, 0, stream>>>(x, R, B, x1, NN);
        edge_k<<<(NE * 64) / 256, 256, 0, stream>>>(x, W, src, dst, et, cnt, x1, NE);
        root_k<<<(NN * 64) / 256 + 1, 256, 0, stream>>>(x1, R + DIM * DIM, B + DIM, out, NN);
        edge_k<<<(NE * 64) / 256, 256, 0, stream>>>(x1, W + NREL * DIM * DIM, src, dst, et, cnt, out, NE);
    }
}

// Round 5
// 557.392 us; speedup vs baseline: 3.7192x; 1.2054x over previous
//
#include <hip/hip_runtime.h>

#define NN    100000
#define NE    1600000
#define DIM   64
#define NREL  8
#define NSEG  (NN * NREL)                       // 800000 (dst,rel) segments
#define NTOT  (NSEG + 1)                        // off[] has a sentinel end
#define CHUNK 1024
#define NBLK  ((NTOT + CHUNK - 1) / CHUNK)      // 782
#define KTOT  (9 * DIM)                         // 576: 8 relations + root
#define APAD  (KTOT + 8)                        // 584 bf16: +16B row pad

typedef unsigned short ushort;
using short8 = __attribute__((ext_vector_type(8))) short;
using f32x4  = __attribute__((ext_vector_type(4))) float;

__device__ __forceinline__ ushort f2bf(float v) {   // f32 -> bf16 RNE
    unsigned b = __float_as_uint(v);
    return (ushort)((b + 0x7FFFu + ((b >> 16) & 1u)) >> 16);
}

// exclusive prefix over blockDim.x values
__device__ __forceinline__ int block_exscan(int v, int* lds) {
    int tid = threadIdx.x;
    lds[tid] = v;
    __syncthreads();
    for (int s = 1; s < (int)blockDim.x; s <<= 1) {
        int t = (tid >= s) ? lds[tid - s] : 0;
        __syncthreads();
        lds[tid] += t;
        __syncthreads();
    }
    return lds[tid] - v;
}

// ---------------- CSR build ----------------
__global__ __launch_bounds__(256) void count_k(const int* __restrict__ dst,
                                               const int* __restrict__ et,
                                               int* __restrict__ cnt, int E) {
    int i = blockIdx.x * 256 + threadIdx.x;
    if (i < E) atomicAdd(&cnt[dst[i] * NREL + et[i]], 1);
}

__global__ __launch_bounds__(256) void scanA(const int* __restrict__ cnt,
                                             int* __restrict__ bsum) {
    __shared__ int lds[256];
    int base = blockIdx.x * CHUNK + threadIdx.x * 4;
    int s = 0;
#pragma unroll
    for (int j = 0; j < 4; ++j) { int i = base + j; if (i < NSEG) s += cnt[i]; }
    int e = block_exscan(s, lds);
    if (threadIdx.x == 255) bsum[blockIdx.x] = e + s;
}

__global__ __launch_bounds__(1024) void scanB(int* __restrict__ bsum) {
    __shared__ int lds[1024];
    int v = (threadIdx.x < NBLK) ? bsum[threadIdx.x] : 0;
    int e = block_exscan(v, lds);
    if (threadIdx.x < NBLK) bsum[threadIdx.x] = e;
}

__global__ __launch_bounds__(256) void scanC(const int* __restrict__ cnt,
                                             const int* __restrict__ bsum,
                                             int* __restrict__ off,
                                             int* __restrict__ cur) {
    __shared__ int lds[256];
    int base = blockIdx.x * CHUNK + threadIdx.x * 4;
    int v[4]; int s = 0;
#pragma unroll
    for (int j = 0; j < 4; ++j) { int i = base + j; v[j] = (i < NSEG) ? cnt[i] : 0; s += v[j]; }
    int e = block_exscan(s, lds) + bsum[blockIdx.x];
#pragma unroll
    for (int j = 0; j < 4; ++j) {
        int i = base + j;
        if (i < NSEG)       { off[i] = e; cur[i] = e; e += v[j]; }
        else if (i == NSEG) { off[i] = e; }                       // sentinel = NE
    }
}

__global__ __launch_bounds__(256) void scatter_k(const int* __restrict__ src,
                                                 const int* __restrict__ dst,
                                                 const int* __restrict__ et,
                                                 int* __restrict__ cur,
                                                 int* __restrict__ es, int E) {
    int i = blockIdx.x * 256 + threadIdx.x;
    if (i < E) {
        int c = dst[i] * NREL + et[i];
        int p = atomicAdd(&cur[c], 1);
        es[p] = src[i];
    }
}

// ---------------- B-stack transpose: Bt[l][n][k] = Bs[l][k][n] in bf16 ----------------
__global__ __launch_bounds__(256) void btk(const float* __restrict__ W,
                                           const float* __restrict__ R,
                                           ushort* __restrict__ BtG) {
    int idx = blockIdx.x * 256 + threadIdx.x;     // [2][64][576]
    if (idx >= 2 * DIM * KTOT) return;
    int k = idx % KTOT;
    int n = (idx / KTOT) & (DIM - 1);
    int l = idx / (KTOT * DIM);
    float v;
    if (k < 8 * DIM) v = W[(((size_t)l * NREL + (k >> 6)) * DIM + (k & 63)) * DIM + n];
    else             v = R[((size_t)l * DIM + (k - 8 * DIM)) * DIM + n];
    BtG[idx] = f2bf(v);
}

// ---------------- BIG path: standalone aggregation (wave per dst) ----------------
// No LDS, ~40 VGPR -> 8 waves/SIMD. 8-deep pipelined gather, writes bf16 A row.
__global__ __launch_bounds__(256, 8) void agg_k(
    const float* __restrict__ xin, const int* __restrict__ off,
    const int* __restrict__ es, ushort* __restrict__ Ag)
{
    const int lane = threadIdx.x & 63;
    const int wv   = threadIdx.x >> 6;
    const int dst  = blockIdx.x * 4 + wv;
    if (dst >= NN) return;
    const int c0 = dst * NREL;
    int offv  = off[c0 + min(lane, 8)];                 // lanes 0..8 = seg bounds
    int pBase = __builtin_amdgcn_readfirstlane(offv);
    int pEnd  = __builtin_amdgcn_readlane(offv, 8);
    ushort* Arow = Ag + (size_t)dst * KTOT;

    float xroot = xin[(size_t)dst * DIM + lane];        // issue early

    int idsbase = pBase;
    int ids = es[min(idsbase + lane, NE - 1)];

    float q0 = 0.f, q1 = 0.f, q2 = 0.f, q3 = 0.f,
          q4 = 0.f, q5 = 0.f, q6 = 0.f, q7 = 0.f;
    {   // prime 8-deep pipeline (idx < 64 guaranteed)
        int pf = pBase;
#define PRIME(Q) if (pf < pEnd) { int idx = pf - idsbase;                     \
        int sv = __builtin_amdgcn_readlane(ids, idx);                         \
        Q = xin[(size_t)sv * DIM + lane]; } ++pf;
        PRIME(q0) PRIME(q1) PRIME(q2) PRIME(q3)
        PRIME(q4) PRIME(q5) PRIME(q6) PRIME(q7)
#undef PRIME
    }
    int seg = 0, segStart = pBase, p = pBase;
    int se = __builtin_amdgcn_readlane(offv, 1);
    float acc = 0.f;

#define STEP(Q) {                                                             \
        while (p == se) {   /* wave-uniform flush (handles empty segs) */     \
            int n = se - segStart;                                            \
            float invn = (n > 0) ? 1.0f / (float)n : 0.f;                     \
            Arow[seg * DIM + lane] = f2bf(acc * invn);                        \
            acc = 0.f; segStart = p;                                          \
            if (++seg >= NREL) goto agg_done;                                 \
            se = __builtin_amdgcn_readlane(offv, seg + 1);                    \
        }                                                                     \
        acc += Q;                                                             \
        int pn = p + 8;                                                       \
        if (pn < pEnd) {                                                      \
            int idx = pn - idsbase;                                           \
            if (idx >= 64) { idsbase = pn;                                    \
                ids = es[min(idsbase + lane, NE - 1)]; idx = 0; }             \
            int sv = __builtin_amdgcn_readlane(ids, idx);                     \
            Q = xin[(size_t)sv * DIM + lane];                                 \
        }                                                                     \
        ++p; }

    for (;;) { STEP(q0) STEP(q1) STEP(q2) STEP(q3)
               STEP(q4) STEP(q5) STEP(q6) STEP(q7) }
agg_done: ;
#undef STEP

    Arow[8 * DIM + lane] = f2bf(xroot);                 // root slot
}

// ---------------- BIG path: GEMM  C[64x64] = A[64x576] @ Bstack[576x64] ----------------
__global__ __launch_bounds__(512, 4) void gemm_k(
    const ushort* __restrict__ Ag, const ushort* __restrict__ BtG,
    const float* __restrict__ bias, float* __restrict__ out)
{
    __shared__ ushort A[64 * APAD];
    const int tid  = threadIdx.x;
    const int base = blockIdx.x * 64;

    // stage 64 rows of Ag -> padded LDS (thread = (row, chunk-group))
    {
        const int srow = tid >> 3, scg = tid & 7;
        const ushort* gsrc = Ag + (size_t)min(base + srow, NN - 1) * KTOT + scg * 8;
        ushort* ldst = &A[srow * APAD + scg * 8];
#pragma unroll
        for (int j = 0; j < 9; ++j)
            *(short8*)(ldst + j * 64) = *(const short8*)(gsrc + j * 64);
    }
    __syncthreads();

    const int lane = tid & 63, wv = tid >> 6;
    const int l15 = lane & 15, hw = lane >> 4;
    const int tid0 = wv * 2;                 // two N-adjacent 16x16 tiles per wave
    const int tm = tid0 >> 2, tn0 = tid0 & 3;
    const ushort* Arow = &A[(tm * 16 + l15) * APAD + hw * 8];
    const ushort* B0   = &BtG[(size_t)(tn0 * 16 + l15) * KTOT + hw * 8];
    const ushort* B1   = B0 + 16 * KTOT;
    f32x4 acc0 = {0.f, 0.f, 0.f, 0.f}, acc1 = {0.f, 0.f, 0.f, 0.f};
#pragma unroll
    for (int ks = 0; ks < KTOT / 32; ++ks) {         // 18 K-steps of 32
        short8 af = *(const short8*)(Arow + ks * 32);
        short8 b0 = *(const short8*)(B0 + ks * 32);
        short8 b1 = *(const short8*)(B1 + ks * 32);
        acc0 = __builtin_amdgcn_mfma_f32_16x16x32_bf16(af, b0, acc0, 0, 0, 0);
        acc1 = __builtin_amdgcn_mfma_f32_16x16x32_bf16(af, b1, acc1, 0, 0, 0);
    }
    // C/D: col = lane&15, row = (lane>>4)*4 + reg   [m89-verified]
    int col0 = tn0 * 16 + l15;
    int r0   = tm * 16 + hw * 4;
    float bv0 = bias[col0], bv1 = bias[col0 + 16];
#pragma unroll
    for (int j = 0; j < 4; ++j) {
        int row = base + r0 + j;
        if (row < NN) {
            out[(size_t)row * DIM + col0]      = acc0[j] + bv0;
            out[(size_t)row * DIM + col0 + 16] = acc1[j] + bv1;
        }
    }
}

// ---------------- MID path: round-4 fused kernel ----------------
__global__ __launch_bounds__(512, 4) void layer_k(
    const float* __restrict__ xin, const ushort* __restrict__ BtG,
    const float* __restrict__ bias, const int* __restrict__ off,
    const int* __restrict__ es, float* __restrict__ out)
{
    __shared__ ushort A[64 * APAD];
    const int lane = threadIdx.x & 63;
    const int wv   = threadIdx.x >> 6;
    const int base = blockIdx.x * 64;
    const int d0   = base + wv * 8;
    const int nds  = min(8, NN - d0);
    ushort* Aw = &A[wv * 8 * APAD];

    if (nds > 0) {
        const int c0   = d0 * NREL;
        const int nseg = nds * NREL;
        int s1v = off[min(c0 + lane + 1, NSEG)];
        int pBase = off[min(c0, NSEG)];
        pBase = __builtin_amdgcn_readfirstlane(pBase);
        int pEnd  = __builtin_amdgcn_readlane(s1v, nseg - 1);

        float xroot[8];
#pragma unroll
        for (int i = 0; i < 8; ++i)
            xroot[i] = xin[(size_t)min(d0 + i, NN - 1) * DIM + lane];

        int idsbase = pBase;
        int ids = es[min(idsbase + lane, NE - 1)];

        float q0 = 0.f, q1 = 0.f, q2 = 0.f, q3 = 0.f,
              q4 = 0.f, q5 = 0.f, q6 = 0.f, q7 = 0.f;
        {
            int pf = pBase;
#define PRIME(Q) if (pf < pEnd) { int idx = pf - idsbase;                     \
        int sv = __builtin_amdgcn_readlane(ids, idx);                         \
        Q = xin[(size_t)sv * DIM + lane]; } ++pf;
            PRIME(q0) PRIME(q1) PRIME(q2) PRIME(q3)
            PRIME(q4) PRIME(q5) PRIME(q6) PRIME(q7)
#undef PRIME
        }
        int seg = 0, segStart = pBase, p = pBase;
        int se = __builtin_amdgcn_readlane(s1v, 0);
        float acc = 0.f;

#define STEP(Q) {                                                             \
        while (p == se) {                                                     \
            int n = se - segStart;                                            \
            float invn = (n > 0) ? 1.0f / (float)n : 0.f;                     \
            Aw[(seg >> 3) * APAD + (seg & 7) * DIM + lane] = f2bf(acc * invn);\
            acc = 0.f; segStart = p;                                          \
            if (++seg >= nseg) goto agg_done;                                 \
            se = __builtin_amdgcn_readlane(s1v, seg);                         \
        }                                                                     \
        acc += Q;                                                             \
        int pn = p + 8;                                                       \
        if (pn < pEnd) {                                                      \
            int idx = pn - idsbase;                                           \
            if (idx >= 64) { idsbase = pn;                                    \
                ids = es[min(idsbase + lane, NE - 1)]; idx = 0; }             \
            int sv = __builtin_amdgcn_readlane(ids, idx);                     \
            Q = xin[(size_t)sv * DIM + lane];                                 \
        }                                                                     \
        ++p; }

        for (;;) { STEP(q0) STEP(q1) STEP(q2) STEP(q3)
                   STEP(q4) STEP(q5) STEP(q6) STEP(q7) }
agg_done: ;
#undef STEP

#pragma unroll
        for (int i = 0; i < 8; ++i) {
            if (i < nds) Aw[i * APAD + 8 * DIM + lane] = f2bf(xroot[i]);
            else {
#pragma unroll
                for (int r = 0; r < 9; ++r) Aw[i * APAD + r * DIM + lane] = 0;
            }
        }
    } else {
#pragma unroll
        for (int i = 0; i < 8; ++i)
#pragma unroll
            for (int r = 0; r < 9; ++r) Aw[i * APAD + r * DIM + lane] = 0;
    }
    __syncthreads();

    const int l15 = lane & 15, hw = lane >> 4;
    const int tid0 = wv * 2;
    const int tm = tid0 >> 2, tn0 = tid0 & 3;
    const ushort* Arow = &A[(tm * 16 + l15) * APAD + hw * 8];
    const ushort* B0   = &BtG[(size_t)(tn0 * 16 + l15) * KTOT + hw * 8];
    const ushort* B1   = B0 + 16 * KTOT;
    f32x4 acc0 = {0.f, 0.f, 0.f, 0.f}, acc1 = {0.f, 0.f, 0.f, 0.f};
#pragma unroll
    for (int ks = 0; ks < KTOT / 32; ++ks) {
        short8 af = *(const short8*)(Arow + ks * 32);
        short8 b0 = *(const short8*)(B0 + ks * 32);
        short8 b1 = *(const short8*)(B1 + ks * 32);
        acc0 = __builtin_amdgcn_mfma_f32_16x16x32_bf16(af, b0, acc0, 0, 0, 0);
        acc1 = __builtin_amdgcn_mfma_f32_16x16x32_bf16(af, b1, acc1, 0, 0, 0);
    }
    int col0 = tn0 * 16 + l15;
    int r0   = tm * 16 + hw * 4;
    float bv0 = bias[col0], bv1 = bias[col0 + 16];
#pragma unroll
    for (int j = 0; j < 4; ++j) {
        int row = base + r0 + j;
        if (row < NN) {
            out[(size_t)row * DIM + col0]      = acc0[j] + bv0;
            out[(size_t)row * DIM + col0 + 16] = acc1[j] + bv1;
        }
    }
}

// ---------------- SMALL path: round-1 per-edge ----------------
__global__ __launch_bounds__(256) void root_k(const float* __restrict__ x,
                                              const float* __restrict__ R,
                                              const float* __restrict__ b,
                                              float* __restrict__ out, int N) {
    int wid  = (blockIdx.x * 256 + threadIdx.x) >> 6;
    int lane = threadIdx.x & 63;
    if (wid >= N) return;
    wid = __builtin_amdgcn_readfirstlane(wid);
    const float* xs = x + (size_t)wid * DIM;
    float acc = b[lane];
#pragma unroll
    for (int k = 0; k < DIM; ++k)
        acc = fmaf(xs[k], R[k * DIM + lane], acc);
    out[(size_t)wid * DIM + lane] = acc;
}

__global__ __launch_bounds__(256) void edge_k(const float* __restrict__ x,
                                              const float* __restrict__ W,
                                              const int* __restrict__ srcv,
                                              const int* __restrict__ dstv,
                                              const int* __restrict__ etv,
                                              const int* __restrict__ cnt,
                                              float* __restrict__ out, int E) {
    int wid  = (blockIdx.x * 256 + threadIdx.x) >> 6;
    int lane = threadIdx.x & 63;
    if (wid >= E) return;
    int s = __builtin_amdgcn_readfirstlane(srcv[wid]);
    int d = __builtin_amdgcn_readfirstlane(dstv[wid]);
    int t = __builtin_amdgcn_readfirstlane(etv[wid]);
    const float* xs = x + (size_t)s * DIM;
    const float* w  = W + (size_t)t * DIM * DIM;
    float acc = 0.f;
#pragma unroll
    for (int k = 0; k < DIM; ++k)
        acc = fmaf(xs[k], w[k * DIM + lane], acc);
    float nrm = 1.0f / fmaxf((float)cnt[d * NREL + t], 1.0f);
    atomicAdd(&out[(size_t)d * DIM + lane], acc * nrm);
}

// ---------------- launch ----------------
extern "C" void kernel_launch(void* const* d_in, const int* in_sizes, int n_in,
                              void* d_out, int out_size, void* d_ws, size_t ws_size,
                              hipStream_t stream) {
    const float* x  = (const float*)d_in[0];   // [N, 64]
    const float* W  = (const float*)d_in[1];   // [2, 8, 64, 64]
    const float* R  = (const float*)d_in[2];   // [2, 64, 64]
    const float* B  = (const float*)d_in[3];   // [2, 64]
    const int*   ei = (const int*)d_in[4];     // [2, E]
    const int*   et = (const int*)d_in[5];     // [E]
    const int* src = ei;
    const int* dst = ei + NE;
    float* out = (float*)d_out;
    char* ws = (char*)d_ws;

    const size_t BIG_WS  = 150560000;
    const size_t FAST_WS = 41604096;

    if (ws_size >= BIG_WS) {
        // BIG layout: x1 | off | es | Ag (cnt,cur alias) | BtG | bsum
        float*  x1  = (float*)(ws + 0);              // 25,600,000
        int*    off = (int*)  (ws + 25600000);       //  3,200,004
        int*    es  = (int*)  (ws + 28800016);       //  6,400,000
        ushort* Ag  = (ushort*)(ws + 35200016);      // 115,200,000
        int*    cnt = (int*)  (ws + 35200016);       // alias (dead before agg)
        int*    cur = (int*)  (ws + 38400016);       // alias (dead before agg)
        ushort* BtG = (ushort*)(ws + 150400016);     //    147,456
        int*    bsum= (int*)  (ws + 150547472);      //      3,128

        hipMemsetAsync(cnt, 0, sizeof(int) * NSEG, stream);
        count_k<<<(NE + 255) / 256, 256, 0, stream>>>(dst, et, cnt, NE);
        scanA<<<NBLK, 256, 0, stream>>>(cnt, bsum);
        scanB<<<1, 1024, 0, stream>>>(bsum);
        scanC<<<NBLK, 256, 0, stream>>>(cnt, bsum, off, cur);
        scatter_k<<<(NE + 255) / 256, 256, 0, stream>>>(src, dst, et, cur, es, NE);
        btk<<<(2 * DIM * KTOT + 255) / 256, 256, 0, stream>>>(W, R, BtG);

        int gblk = (NN + 63) / 64;   // 1563
        agg_k<<<(NN + 3) / 4, 256, 0, stream>>>(x, off, es, Ag);
        gemm_k<<<gblk, 512, 0, stream>>>(Ag, BtG, B, x1);
        agg_k<<<(NN + 3) / 4, 256, 0, stream>>>(x1, off, es, Ag);
        gemm_k<<<gblk, 512, 0, stream>>>(Ag, BtG + DIM * KTOT, B + DIM, out);
    } else if (ws_size >= FAST_WS) {
        // round-4 layout
        float*  x1  = (float*)(ws + 0);
        int*    cnt = (int*)  (ws + 25600000);
        int*    off = (int*)  (ws + 28800000);
        int*    cur = (int*)  (ws + 32000016);
        int*    es  = (int*)  (ws + 35200016);
        int*    bsum= (int*)  (ws + 41600016);
        ushort* BtG = (ushort*)(ws + 32000016);      // alias over cur

        hipMemsetAsync(cnt, 0, sizeof(int) * NSEG, stream);
        count_k<<<(NE + 255) / 256, 256, 0, stream>>>(dst, et, cnt, NE);
        scanA<<<NBLK, 256, 0, stream>>>(cnt, bsum);
        scanB<<<1, 1024, 0, stream>>>(bsum);
        scanC<<<NBLK, 256, 0, stream>>>(cnt, bsum, off, cur);
        scatter_k<<<(NE + 255) / 256, 256, 0, stream>>>(src, dst, et, cur, es, NE);
        btk<<<(2 * DIM * KTOT + 255) / 256, 256, 0, stream>>>(W, R, BtG);

        int nblk = (NN + 63) / 64;
        layer_k<<<nblk, 512, 0, stream>>>(x,  BtG,              B,       off, es, x1);
        layer_k<<<nblk, 512, 0, stream>>>(x1, BtG + DIM * KTOT, B + DIM, off, es, out);
    } else {
        float* x1  = (float*)ws;
        int*   cnt = (int*)(ws + 25600000);
        hipMemsetAsync(cnt, 0, sizeof(int) * NSEG, stream);
        count_k<<<(NE + 255) / 256, 256, 0, stream>>>(dst, et, cnt, NE);
        root_k<<<(NN * 64) / 256 + 1, 256, 0, stream>>>(x, R, B, x1, NN);
        edge_k<<<(NE * 64) / 256, 256, 0, stream>>>(x, W, src, dst, et, cnt, x1, NE);
        root_k<<<(NN * 64) / 256 + 1, 256, 0, stream>>>(x1, R + DIM * DIM, B + DIM, out, NN);
        edge_k<<<(NE * 64) / 256, 256, 0, stream>>>(x1, W + NREL * DIM * DIM, src, dst, et, cnt, out, NE);
    }
}